// Round 2
// baseline (1009.386 us; speedup 1.0000x reference)
//
#include <hip/hip_runtime.h>
#include <stdint.h>

// SparseConv3d: x [4,64,64,64,64] f32, w [64,64,3,3,3] f32 -> out [4,64,64,64,64] f32
// Dense-output implicit GEMM: block = 1 wave = one x-line (b,z,y): M=64 voxels, N=64 co,
// K = 27 taps x 64 ci. Strips (dz,dy) are contiguous 8KB rows of channels-last bf16 xt,
// register-pipelined through one padded LDS strip. Dense line writes -> no memset/RFO.

#define R3 262144           // 64^3
#define NVOX (4 * R3)
#define WSW_ELEMS (27 * 2 * 4 * 64 * 8)

typedef __attribute__((ext_vector_type(4))) float f32x4;
typedef __attribute__((ext_vector_type(8))) short short8;

static __device__ inline unsigned short f2bf(float f) {
    union { float f; unsigned u; } v; v.f = f;
    unsigned u = v.u;
    return (unsigned short)((u + 0x7fffu + ((u >> 16) & 1u)) >> 16);  // RNE
}

// ---- weight swizzle: B-fragment order for mfma_f32_16x16x32_bf16 (round-1 verified) ----
// layout: [tap 27][kc 2][nt 4][lane 64][j 8]; lane holds B[k=(lane>>4)*8+j][n=lane&15]
__global__ void wprep(const float* __restrict__ w, unsigned short* __restrict__ wsw) {
    int e = blockIdx.x * 256 + threadIdx.x;
    if (e >= WSW_ELEMS) return;
    int j    = e & 7;
    int lane = (e >> 3) & 63;
    int nt   = (e >> 9) & 3;
    int kc   = (e >> 11) & 1;
    int tap  = e >> 12;
    int co = nt * 16 + (lane & 15);
    int ci = kc * 32 + ((lane >> 4) * 8) + j;
    wsw[e] = f2bf(w[(co * 64 + ci) * 27 + tap]);
}

// ---- pass 1: x -> channels-last bf16 xt (voxel-major), exact fp32 mask bits ----
__global__ void __launch_bounds__(256) xprep(const float* __restrict__ x,
                                             unsigned int* __restrict__ xt_u32,
                                             unsigned int* __restrict__ maskbits) {
    __shared__ unsigned int lds[256 * 33];     // [voxel 256][ci-pair 32], stride 33
    int t = threadIdx.x;
    int v = blockIdx.x * 256 + t;
    int b = v >> 18;
    int s = v & (R3 - 1);
    const float* xb = x + (size_t)b * (64 * R3) + s;
    bool active = false;
#pragma unroll
    for (int c2 = 0; c2 < 32; ++c2) {
        float f0 = xb[(size_t)(2 * c2) * R3];
        float f1 = xb[(size_t)(2 * c2 + 1) * R3];
        active |= (f0 != 0.f) | (f1 != 0.f);
        lds[t * 33 + c2] = (unsigned)f2bf(f0) | ((unsigned)f2bf(f1) << 16);
    }
    __syncthreads();
    unsigned int* dst = xt_u32 + (size_t)blockIdx.x * 8192;
#pragma unroll
    for (int i = 0; i < 32; ++i) {
        int g = i * 256 + t;
        dst[g] = lds[(g >> 5) * 33 + (g & 31)];   // xt_u32[v*32 + c2]
    }
    unsigned long long bal = __ballot(active);
    if ((t & 63) == 0) {
        unsigned base = ((unsigned)blockIdx.x * 256 + (t >> 6) * 64) >> 5;
        maskbits[base]     = (unsigned)bal;
        maskbits[base + 1] = (unsigned)(bal >> 32);
    }
}

// ---- pass 2: dense line GEMM ----
__global__ void __launch_bounds__(64, 3) sconv_dense(const unsigned short* __restrict__ xt,
                                                     const unsigned short* __restrict__ wsw,
                                                     const unsigned int* __restrict__ maskbits,
                                                     float* __restrict__ out) {
    // strip: 66 rows (x' = -1..64) x 64 bf16, padded row stride 72 shorts (144 B)
    __shared__ __align__(16) unsigned short smem[66 * 72];   // 9504 B; reused as epi f32
    int bid = blockIdx.x;
    int lin = (bid & 7) * 2048 + (bid >> 3);   // XCD-contiguous line regions
    int b = lin >> 12, z = (lin >> 6) & 63, y = lin & 63;
    int l = threadIdx.x, q = l >> 4, lm = l & 15;

    // zero pad rows 0 and 65 (only cols 0..63 are ever read)
    unsigned int* sw = (unsigned int*)smem;
    if (l < 32) sw[l] = 0u;
    else        sw[65 * 36 + (l - 32)] = 0u;

    f32x4 acc[4][4] = {};
    uint4 rg[8];

    // prologue: load strip 0
    bool vcur;
    {
        int zp = z + 0 - 1, yp = y + 0 - 1;
        vcur = ((unsigned)zp < 64u) & ((unsigned)yp < 64u);
        if (vcur) {
            const uint4* g = (const uint4*)(xt + ((size_t)b * R3 + zp * 4096 + yp * 64) * 64);
#pragma unroll
            for (int k = 0; k < 8; ++k) rg[k] = g[k * 64 + l];
        }
    }

    for (int s = 0; s < 9; ++s) {
        // commit current strip regs -> LDS (rows 1..64)
        if (vcur) {
#pragma unroll
            for (int k = 0; k < 8; ++k) {
                int c = k * 64 + l;                         // 16B chunk id
                int row = (c >> 3) + 1;
                *(uint4*)&smem[row * 72 + (c & 7) * 8] = rg[k];
            }
        }
        // prefetch next strip into regs (latency hidden behind this phase's MFMAs)
        bool vnext = false;
        if (s < 8) {
            int sn = s + 1;
            int zp = z + sn / 3 - 1, yp = y + sn % 3 - 1;
            vnext = ((unsigned)zp < 64u) & ((unsigned)yp < 64u);
            if (vnext) {
                const uint4* g = (const uint4*)(xt + ((size_t)b * R3 + zp * 4096 + yp * 64) * 64);
#pragma unroll
                for (int k = 0; k < 8; ++k) rg[k] = g[k * 64 + l];
            }
        }
        // compute phase s: taps (dz,dy,dx=0..2), 96 MFMA
        if (vcur) {
            int tapb = (s / 3) * 9 + (s % 3) * 3;
#pragma unroll
            for (int dx = 0; dx < 3; ++dx) {
#pragma unroll
                for (int kc = 0; kc < 2; ++kc) {
                    short8 afr[4], bfr[4];
#pragma unroll
                    for (int nt = 0; nt < 4; ++nt)
                        bfr[nt] = *(const short8*)(wsw +
                            (((size_t)((tapb + dx) * 8 + kc * 4 + nt)) * 64 + l) * 8);
#pragma unroll
                    for (int mt = 0; mt < 4; ++mt) {
                        int row = mt * 16 + lm + dx;        // x' = x + dx - 1 -> LDS row x+dx
                        afr[mt] = *(const short8*)&smem[row * 72 + kc * 32 + q * 8];
                    }
#pragma unroll
                    for (int mt = 0; mt < 4; ++mt)
#pragma unroll
                        for (int nt = 0; nt < 4; ++nt)
                            acc[mt][nt] = __builtin_amdgcn_mfma_f32_16x16x32_bf16(
                                afr[mt], bfr[nt], acc[mt][nt], 0, 0, 0);
                }
            }
        }
        vcur = vnext;
    }

    // epilogue: LDS-transpose 16x64 chunks -> coalesced line stores, mask from fp32 bits
    long long v0 = (long long)b * R3 + z * 4096 + y * 64;
    unsigned mw0 = maskbits[(v0 >> 5)];
    unsigned mw1 = maskbits[(v0 >> 5) + 1];
    float* epi = (float*)smem;                 // [co 64][x_local 16 + 1 pad]
#pragma unroll
    for (int mt = 0; mt < 4; ++mt) {
#pragma unroll
        for (int nt = 0; nt < 4; ++nt)
#pragma unroll
            for (int r = 0; r < 4; ++r)
                epi[(nt * 16 + lm) * 17 + q * 4 + r] = acc[mt][nt][r];
        unsigned mw = (mt < 2) ? mw0 : mw1;
#pragma unroll
        for (int rr = 0; rr < 16; ++rr) {
            int co = rr * 4 + q;
            float val = epi[co * 17 + lm];
            int xg = mt * 16 + lm;
            val = ((mw >> (xg & 31)) & 1u) ? val : 0.0f;
            out[(size_t)(b * 64 + co) * R3 + z * 4096 + y * 64 + xg] = val;
        }
    }
}

// ---- fallback (ws too small): dense fp32 direct conv (round-1, correct) ----
__global__ void __launch_bounds__(64) fallback_conv(const float* __restrict__ x,
                                                    const float* __restrict__ wt,
                                                    float* __restrict__ out) {
    __shared__ float rowb[66];
    int bid = blockIdx.x;
    int y = bid & 63, z = (bid >> 6) & 63, co = (bid >> 12) & 63, b = bid >> 18;
    int t = threadIdx.x;
    float acc = 0.f;
    bool active = false;
    for (int ci = 0; ci < 64; ++ci) {
        const float* xp = x + ((size_t)(b * 64 + ci)) * R3;
        const float* wp = wt + ((size_t)(co * 64 + ci)) * 27;
        for (int dz = -1; dz <= 1; ++dz) {
            int nz = z + dz;
            bool okz = (unsigned)nz < 64u;
            for (int dy = -1; dy <= 1; ++dy) {
                int ny = y + dy;
                bool ok = okz && ((unsigned)ny < 64u);
                float v = ok ? xp[nz * 4096 + ny * 64 + t] : 0.f;
                rowb[t + 1] = v;
                if (t == 0) { rowb[0] = 0.f; rowb[65] = 0.f; }
                __syncthreads();
                if (dz == 0 && dy == 0) active |= (rowb[t + 1] != 0.f);
                const float* wq = wp + (dz + 1) * 9 + (dy + 1) * 3;
                acc += rowb[t] * wq[0] + rowb[t + 1] * wq[1] + rowb[t + 2] * wq[2];
                __syncthreads();
            }
        }
    }
    out[((size_t)(b * 64 + co)) * R3 + z * 4096 + y * 64 + t] = active ? acc : 0.f;
}

extern "C" void kernel_launch(void* const* d_in, const int* in_sizes, int n_in,
                              void* d_out, int out_size, void* d_ws, size_t ws_size,
                              hipStream_t stream) {
    const float* x = (const float*)d_in[0];
    const float* w = (const float*)d_in[1];
    float* out = (float*)d_out;

    const size_t XT_BYTES = (size_t)NVOX * 64 * 2;        // 128 MB bf16 channels-last
    const size_t MB_OFF   = XT_BYTES;                     // mask bits: 128 KB
    const size_t WSW_OFF  = MB_OFF + NVOX / 8;
    const size_t NEED     = WSW_OFF + (size_t)WSW_ELEMS * 2;

    if (ws_size < NEED) {
        fallback_conv<<<NVOX, 64, 0, stream>>>(x, w, out);
        return;
    }

    unsigned int*   xt_u32 = (unsigned int*)d_ws;
    unsigned int*   mbits  = (unsigned int*)((char*)d_ws + MB_OFF);
    unsigned short* wsw    = (unsigned short*)((char*)d_ws + WSW_OFF);

    wprep<<<WSW_ELEMS / 256, 256, 0, stream>>>(w, wsw);
    xprep<<<NVOX / 256, 256, 0, stream>>>(x, xt_u32, mbits);
    sconv_dense<<<NVOX / 64, 64, 0, stream>>>((const unsigned short*)xt_u32, wsw, mbits, out);
}

// Round 3
// 1001.926 us; speedup vs baseline: 1.0074x; 1.0074x over previous
//
#include <hip/hip_runtime.h>
#include <stdint.h>

// SparseConv3d: x [4,64,64,64,64] f32, w [64,64,3,3,3] f32 -> out [4,64,64,64,64] f32
// Dense-output implicit GEMM, 1 wave = one x-line (b,z,y): M=64 x, N=64 co, K=27 taps x 64 ci.
// xt is channels-last bf16, chunk-XOR-preswizzled so strip commits are linear and
// LDS A-fragment reads are conflict-free. Epilogue writes full 256-B contiguous runs.

#define R3 262144           // 64^3
#define NVOX (4 * R3)
#define WSW_ELEMS (27 * 2 * 4 * 64 * 8)

typedef __attribute__((ext_vector_type(4))) float f32x4;
typedef __attribute__((ext_vector_type(8))) short short8;

static __device__ inline unsigned short f2bf(float f) {
    union { float f; unsigned u; } v; v.f = f;
    unsigned u = v.u;
    return (unsigned short)((u + 0x7fffu + ((u >> 16) & 1u)) >> 16);  // RNE
}

// ---- weight swizzle: B-fragment order for mfma_f32_16x16x32_bf16 (verified r1/r2) ----
// layout: [tap 27][kc 2][nt 4][lane 64][j 8]; lane holds B[k=(lane>>4)*8+j][n=lane&15]
__global__ void wprep(const float* __restrict__ w, unsigned short* __restrict__ wsw) {
    int e = blockIdx.x * 256 + threadIdx.x;
    if (e >= WSW_ELEMS) return;
    int j    = e & 7;
    int lane = (e >> 3) & 63;
    int nt   = (e >> 9) & 3;
    int kc   = (e >> 11) & 1;
    int tap  = e >> 12;
    int co = nt * 16 + (lane & 15);
    int ci = kc * 32 + ((lane >> 4) * 8) + j;
    wsw[e] = f2bf(w[(co * 64 + ci) * 27 + tap]);
}

// ---- pass 1: x -> channels-last bf16 xt (chunk-XOR-preswizzled), mask bits ----
// tile = 256 consecutive voxels; wave w handles channels 16w..16w+15; float4 loads.
__global__ void __launch_bounds__(256) xprep(const float* __restrict__ x,
                                             unsigned int* __restrict__ xt_u32,
                                             unsigned int* __restrict__ maskbits) {
    __shared__ unsigned int lv[64 * 129];   // [c][voxel-pair 128], stride 129 (2-way reads)
    __shared__ unsigned int actv[64];
    int t = threadIdx.x;
    int l = t & 63, w = t >> 6;
    long long v0 = (long long)blockIdx.x * 256;      // 256 | R3 -> single batch
    int b = (int)(v0 >> 18);
    int s0 = (int)(v0 & (R3 - 1));
    if (t < 64) actv[t] = 0u;
    __syncthreads();
    unsigned m4 = 0;
#pragma unroll
    for (int cc = 0; cc < 16; ++cc) {
        int c = w * 16 + cc;
        const float4 f = *(const float4*)(x + ((size_t)(b * 64 + c)) * R3 + s0 + l * 4);
        m4 |= (f.x != 0.f ? 1u : 0u) | (f.y != 0.f ? 2u : 0u) |
              (f.z != 0.f ? 4u : 0u) | (f.w != 0.f ? 8u : 0u);
        lv[c * 129 + 2 * l]     = (unsigned)f2bf(f.x) | ((unsigned)f2bf(f.y) << 16);
        lv[c * 129 + 2 * l + 1] = (unsigned)f2bf(f.z) | ((unsigned)f2bf(f.w) << 16);
    }
    atomicOr(&actv[l], m4);
    __syncthreads();
    unsigned int* dst = xt_u32 + v0 * 32;
#pragma unroll
    for (int i = 0; i < 16; ++i) {
        int vp = i * 8 + (t >> 5);                   // voxel pair 0..127
        int c2 = t & 31;                             // logical ci-pair word
        unsigned a  = lv[(2 * c2) * 129 + vp];
        unsigned bb = lv[(2 * c2 + 1) * 129 + vp];
        unsigned we = (a & 0xffffu) | (bb << 16);    // word for even voxel
        unsigned wo = (a >> 16) | (bb & 0xffff0000u);// word for odd voxel
        int ve = 2 * vp, vo = ve + 1;
        int ke = (((s0 + ve) & 63) + 1) & 7;         // chunk XOR keys
        int ko = (((s0 + vo) & 63) + 1) & 7;
        dst[ve * 32 + (((c2 >> 2) ^ ke) << 2) + (c2 & 3)] = we;
        dst[vo * 32 + (((c2 >> 2) ^ ko) << 2) + (c2 & 3)] = wo;
    }
    if (t < 8) {
        unsigned wm = 0;
#pragma unroll
        for (int g = 0; g < 8; ++g) wm |= (actv[t * 8 + g] & 0xFu) << (4 * g);
        maskbits[blockIdx.x * 8 + t] = wm;
    }
}

// ---- pass 2: dense line GEMM ----
__global__ void __launch_bounds__(64, 3) sconv_dense(const unsigned short* __restrict__ xt,
                                                     const unsigned short* __restrict__ wsw,
                                                     const unsigned int* __restrict__ maskbits,
                                                     float* __restrict__ out) {
    // strip: 66 rows x 64 bf16 (128 B/row, 8 chunks), XOR-swizzled; reused as epi f32 [32][67]
    __shared__ __align__(16) unsigned char smem_raw[32 * 67 * 4];   // 8576 B >= 8448
    unsigned short* smem = (unsigned short*)smem_raw;
    int bid = blockIdx.x;
    int lin = (bid & 7) * 2048 + (bid >> 3);         // XCD-contiguous line regions
    int b = lin >> 12, z = (lin >> 6) & 63, y = lin & 63;
    int l = threadIdx.x, q = l >> 4, lm = l & 15;

    // zero boundary rows 0 (x'=-1) and 65 (x'=64): 32 u32 each
    unsigned int* sw = (unsigned int*)smem;
    if (l < 32) sw[l] = 0u;
    else        sw[65 * 32 + (l - 32)] = 0u;

    f32x4 acc[4][4] = {};
    uint4 rg[8];

    bool vcur;
    {
        int zp = z - 1, yp = y - 1;
        vcur = ((unsigned)zp < 64u) & ((unsigned)yp < 64u);
        if (vcur) {
            const uint4* g = (const uint4*)(xt + ((size_t)b * R3 + zp * 4096 + yp * 64) * 64);
#pragma unroll
            for (int k = 0; k < 8; ++k) rg[k] = g[k * 64 + l];
        }
    }

    for (int s = 0; s < 9; ++s) {
        // commit strip regs -> LDS rows 1..64 (linear: xt is pre-swizzled)
        if (vcur) {
#pragma unroll
            for (int k = 0; k < 8; ++k)
                *(uint4*)&smem[(8 + k * 64 + l) * 8] = rg[k];
        }
        // prefetch next strip
        bool vnext = false;
        if (s < 8) {
            int sn = s + 1;
            int zp = z + sn / 3 - 1, yp = y + sn % 3 - 1;
            vnext = ((unsigned)zp < 64u) & ((unsigned)yp < 64u);
            if (vnext) {
                const uint4* g = (const uint4*)(xt + ((size_t)b * R3 + zp * 4096 + yp * 64) * 64);
#pragma unroll
                for (int k = 0; k < 8; ++k) rg[k] = g[k * 64 + l];
            }
        }
        // compute: taps (dz,dy,dx 0..2), 96 MFMA
        if (vcur) {
            int tapb = (s / 3) * 9 + (s % 3) * 3;
#pragma unroll
            for (int dx = 0; dx < 3; ++dx) {
#pragma unroll
                for (int kc = 0; kc < 2; ++kc) {
                    short8 afr[4], bfr[4];
#pragma unroll
                    for (int nt = 0; nt < 4; ++nt)
                        bfr[nt] = *(const short8*)(wsw +
                            (((size_t)((tapb + dx) * 8 + kc * 4 + nt)) * 64 + l) * 8);
#pragma unroll
                    for (int mt = 0; mt < 4; ++mt) {
                        int row = mt * 16 + lm + dx;                 // LDS row = x+dx
                        int phys = (kc * 4 + q) ^ (row & 7);         // XOR de-swizzle
                        afr[mt] = *(const short8*)&smem[row * 64 + phys * 8];
                    }
#pragma unroll
                    for (int mt = 0; mt < 4; ++mt)
#pragma unroll
                        for (int nt = 0; nt < 4; ++nt)
                            acc[mt][nt] = __builtin_amdgcn_mfma_f32_16x16x32_bf16(
                                afr[mt], bfr[nt], acc[mt][nt], 0, 0, 0);
                }
            }
        }
        vcur = vnext;
    }

    // epilogue: two half-passes [32 co][67] -> full-line 256-B contiguous stores
    long long v0 = (long long)b * R3 + z * 4096 + y * 64;
    unsigned mw0 = maskbits[v0 >> 5];
    unsigned mw1 = maskbits[(v0 >> 5) + 1];
    unsigned keep = (l < 32) ? ((mw0 >> l) & 1u) : ((mw1 >> (l - 32)) & 1u);
    float* epi = (float*)smem_raw;                   // [co_local 32][67]
    float* obase = out + (size_t)(b * 64) * R3 + z * 4096 + y * 64;
#pragma unroll
    for (int h = 0; h < 2; ++h) {
#pragma unroll
        for (int ntl = 0; ntl < 2; ++ntl) {
            int nt = h * 2 + ntl;
#pragma unroll
            for (int mt = 0; mt < 4; ++mt)
#pragma unroll
                for (int r = 0; r < 4; ++r)
                    epi[(ntl * 16 + lm) * 67 + mt * 16 + q * 4 + r] = acc[mt][nt][r];
        }
#pragma unroll
        for (int cl = 0; cl < 32; ++cl) {
            float vv = epi[cl * 67 + l];
            obase[(size_t)(h * 32 + cl) * R3 + l] = keep ? vv : 0.0f;
        }
    }
}

// ---- fallback (ws too small): dense fp32 direct conv (round-1, correct) ----
__global__ void __launch_bounds__(64) fallback_conv(const float* __restrict__ x,
                                                    const float* __restrict__ wt,
                                                    float* __restrict__ out) {
    __shared__ float rowb[66];
    int bid = blockIdx.x;
    int y = bid & 63, z = (bid >> 6) & 63, co = (bid >> 12) & 63, b = bid >> 18;
    int t = threadIdx.x;
    float acc = 0.f;
    bool active = false;
    for (int ci = 0; ci < 64; ++ci) {
        const float* xp = x + ((size_t)(b * 64 + ci)) * R3;
        const float* wp = wt + ((size_t)(co * 64 + ci)) * 27;
        for (int dz = -1; dz <= 1; ++dz) {
            int nz = z + dz;
            bool okz = (unsigned)nz < 64u;
            for (int dy = -1; dy <= 1; ++dy) {
                int ny = y + dy;
                bool ok = okz && ((unsigned)ny < 64u);
                float v = ok ? xp[nz * 4096 + ny * 64 + t] : 0.f;
                rowb[t + 1] = v;
                if (t == 0) { rowb[0] = 0.f; rowb[65] = 0.f; }
                __syncthreads();
                if (dz == 0 && dy == 0) active |= (rowb[t + 1] != 0.f);
                const float* wq = wp + (dz + 1) * 9 + (dy + 1) * 3;
                acc += rowb[t] * wq[0] + rowb[t + 1] * wq[1] + rowb[t + 2] * wq[2];
                __syncthreads();
            }
        }
    }
    out[((size_t)(b * 64 + co)) * R3 + z * 4096 + y * 64 + t] = active ? acc : 0.f;
}

extern "C" void kernel_launch(void* const* d_in, const int* in_sizes, int n_in,
                              void* d_out, int out_size, void* d_ws, size_t ws_size,
                              hipStream_t stream) {
    const float* x = (const float*)d_in[0];
    const float* w = (const float*)d_in[1];
    float* out = (float*)d_out;

    const size_t XT_BYTES = (size_t)NVOX * 64 * 2;        // 128 MB bf16 channels-last
    const size_t MB_OFF   = XT_BYTES;                     // mask bits: 128 KB
    const size_t WSW_OFF  = MB_OFF + NVOX / 8;
    const size_t NEED     = WSW_OFF + (size_t)WSW_ELEMS * 2;

    if (ws_size < NEED) {
        fallback_conv<<<NVOX, 64, 0, stream>>>(x, w, out);
        return;
    }

    unsigned int*   xt_u32 = (unsigned int*)d_ws;
    unsigned int*   mbits  = (unsigned int*)((char*)d_ws + MB_OFF);
    unsigned short* wsw    = (unsigned short*)((char*)d_ws + WSW_OFF);

    wprep<<<WSW_ELEMS / 256, 256, 0, stream>>>(w, wsw);
    xprep<<<NVOX / 256, 256, 0, stream>>>(x, xt_u32, mbits);
    sconv_dense<<<NVOX / 64, 64, 0, stream>>>((const unsigned short*)xt_u32, wsw, mbits, out);
}